// Round 14
// baseline (380.721 us; speedup 1.0000x reference)
//
#include <hip/hip_runtime.h>
#include <hip/hip_bf16.h>

#define HDIM 128
static constexpr float BN_S = 0.99999500003749968751f; // 1/sqrt(1+1e-5)

typedef float f32x4 __attribute__((ext_vector_type(4)));
typedef short s16x8 __attribute__((ext_vector_type(8)));

union U128 { uint4 u; s16x8 s; };

__device__ __forceinline__ unsigned short f2bs(float f){
    union{float f; unsigned u;} c; c.f = f;
    unsigned r = c.u + 0x7fffu + ((c.u >> 16) & 1u);
    return (unsigned short)(r >> 16);
}
__device__ __forceinline__ float bs2f(unsigned short s){
    union{unsigned u; float f;} c; c.u = ((unsigned)s) << 16;
    return c.f;
}
__device__ __forceinline__ float ulo(unsigned u){ union{unsigned i; float f;} c; c.i = u << 16; return c.f; }
__device__ __forceinline__ float uhi(unsigned u){ union{unsigned i; float f;} c; c.i = u & 0xffff0000u; return c.f; }

// ---------------- zero counters + prepack all weights (one node) ----------------
__global__ __launch_bounds__(256) void k_prepzero(
    const float* __restrict__ linW, const float* __restrict__ cW1,
    const float* __restrict__ cW2, const float* __restrict__ cW3,
    const float* __restrict__ hW1, const float* __restrict__ oW1,
    const float* __restrict__ hW2, const float* __restrict__ oW2,
    unsigned short* __restrict__ wf, unsigned short* __restrict__ p1,
    unsigned short* __restrict__ p2, int* __restrict__ cnt, int N)
{
    int id = blockIdx.x * 256 + threadIdx.x;
    if (id < 65536){
        int mat = id >> 14;
        int el = id & 16383;
        int k = el >> 7, n = el & 127;
        const float* W = (mat == 0) ? linW : (mat == 1) ? cW1 : (mat == 2) ? cW2 : cW3;
        float v = W[k * 128 + n];
        unsigned short hs = f2bs(v);
        unsigned short ls = f2bs(v - bs2f(hs));
        int nt = n >> 4, lanen = n & 15, kc = k >> 5, quad = (k >> 3) & 3, j = k & 7;
        int lane = quad * 16 + lanen;
        size_t base = (size_t)mat * 32768;
        wf[base + (size_t)(((nt * 4 + kc) * 2 + 0) * 64 + lane) * 8 + j] = hs;
        wf[base + (size_t)(((nt * 4 + kc) * 2 + 1) * 64 + lane) * 8 + j] = ls;
    } else if (id < 65536 + 51200){
        int id1 = id - 65536;
        if (id1 < 40960){
            int j = id1 & 7, lane = (id1 >> 3) & 63, kc = (id1 >> 9) & 3, nt = (id1 >> 11) & 3, y = id1 >> 13;
            int k = kc * 32 + (lane >> 4) * 8 + j;
            int n = nt * 16 + (lane & 15);
            float w = (y < 4) ? hW1[(y * 128 + k) * 64 + n] : oW1[k * 64 + n];
            p1[id1] = f2bs(w);
        } else {
            int id2 = id1 - 40960;
            int j = id2 & 7, lane = (id2 >> 3) & 63, kc = (id2 >> 9) & 1, nt = (id2 >> 10) & 1, y = id2 >> 11;
            int k = kc * 32 + (lane >> 4) * 8 + j;
            int n = nt * 16 + (lane & 15);
            float w = (y < 4) ? hW2[(y * 64 + k) * 32 + n] : oW2[k * 32 + n];
            p2[id2] = f2bs(w);
        }
    } else {
        int z = id - (65536 + 51200);
        if (z < N) cnt[z] = 0;
    }
}

// ---------------- scan phase 1: per-1024-chunk sums ----------------
__global__ __launch_bounds__(256) void k_bsum(const int* __restrict__ cnt, int* __restrict__ bsum, int N){
    int b = blockIdx.x, t = threadIdx.x;
    int s = 0;
#pragma unroll
    for (int i = 0; i < 4; ++i){
        int idx = b * 1024 + i * 256 + t;
        if (idx < N) s += cnt[idx];
    }
    for (int off = 32; off; off >>= 1) s += __shfl_down(s, off);
    __shared__ int ws[4];
    if ((t & 63) == 0) ws[t >> 6] = s;
    __syncthreads();
    if (t == 0) bsum[b] = ws[0] + ws[1] + ws[2] + ws[3];
}

// ---------------- scan phase 2: single-block exclusive scan of chunk sums ----------------
__global__ __launch_bounds__(256) void k_bscan(const int* __restrict__ bsum, int* __restrict__ bpre,
                                               int* __restrict__ rowptr, int B, int N, int E){
    __shared__ int arr[256];
    int t = threadIdx.x;
    int v = (t < B) ? bsum[t] : 0;
    arr[t] = v;
    for (int off = 1; off < 256; off <<= 1){
        __syncthreads();
        int x = (t >= off) ? arr[t - off] : 0;
        __syncthreads();
        arr[t] += x;
    }
    __syncthreads();
    if (t < B) bpre[t] = arr[t] - v;
    if (t == 0) rowptr[N] = E;
}

// ---------------- scan phase 3: within-chunk scan + rowptr/dis write ----------------
__global__ __launch_bounds__(1024) void k_scan3(const int* __restrict__ cnt, const int* __restrict__ bpre,
                                                int* __restrict__ rowptr, float* __restrict__ dis, int N){
    __shared__ int arr[1024];
    int b = blockIdx.x, t = threadIdx.x;
    int idx = b * 1024 + t;
    int c = (idx < N) ? cnt[idx] : 0;
    arr[t] = c;
    for (int off = 1; off < 1024; off <<= 1){
        __syncthreads();
        int x = (t >= off) ? arr[t - off] : 0;
        __syncthreads();
        arr[t] += x;
    }
    __syncthreads();
    if (idx < N){
        rowptr[idx] = bpre[b] + arr[t] - c;
        dis[idx] = rsqrtf(1.0f + (float)c);
    }
}

// ---------------- wave-level GEMM: each wave owns 16 rows, no LDS staging ----------------
// MODE 0: A=x, input-BN fold (sing/sinb in LDS), split-A 2-term, epilogue BN+relu -> fp32 hout
// MODE 1: A=h, plain bf16, epilogue raw -> bf16 hwout; no LDS, no barrier
template<int MODE>
__device__ __forceinline__ void gemm_warp(
    int wtile, const float* __restrict__ A, const uint4* __restrict__ wf,
    const float* __restrict__ sing, const float* __restrict__ sinb,
    const float* __restrict__ ebias, const float* __restrict__ eg, const float* __restrict__ eb,
    float* __restrict__ hout, unsigned short* __restrict__ hwout, int nrows)
{
    int l = threadIdx.x & 63;
    int lanen = l & 15, quad = l >> 4;
    int arow_i = wtile * 16 + lanen;
    bool rv = arow_i < nrows;
    const float* arow = A + (size_t)(rv ? arow_i : 0) * 128;

    U128 Ahi[4], Alo[4];
#pragma unroll
    for (int kc = 0; kc < 4; ++kc){
        int k0 = kc * 32 + quad * 8;
        float4 a0 = *(const float4*)&arow[k0];
        float4 a1 = *(const float4*)&arow[k0 + 4];
        if (!rv){ a0 = make_float4(0.f,0.f,0.f,0.f); a1 = make_float4(0.f,0.f,0.f,0.f); }
        float va[8] = {a0.x, a0.y, a0.z, a0.w, a1.x, a1.y, a1.z, a1.w};
        if (MODE == 0){
#pragma unroll
            for (int j = 0; j < 8; ++j) va[j] = va[j] * sing[k0 + j] + sinb[k0 + j];
            unsigned hiw[4], low[4];
#pragma unroll
            for (int p = 0; p < 4; ++p){
                unsigned u0 = __float_as_uint(va[2*p]);
                unsigned u1 = __float_as_uint(va[2*p+1]);
                hiw[p] = (u0 >> 16) | (u1 & 0xffff0000u);
                unsigned short q0 = f2bs(va[2*p]   - __uint_as_float(u0 & 0xffff0000u));
                unsigned short q1 = f2bs(va[2*p+1] - __uint_as_float(u1 & 0xffff0000u));
                low[p] = (unsigned)q0 | ((unsigned)q1 << 16);
            }
            Ahi[kc].u = make_uint4(hiw[0], hiw[1], hiw[2], hiw[3]);
            Alo[kc].u = make_uint4(low[0], low[1], low[2], low[3]);
        } else {
            unsigned hw[4];
#pragma unroll
            for (int p = 0; p < 4; ++p)
                hw[p] = (unsigned)f2bs(va[2*p]) | ((unsigned)f2bs(va[2*p+1]) << 16);
            Ahi[kc].u = make_uint4(hw[0], hw[1], hw[2], hw[3]);
        }
    }

    f32x4 acc[8];
#pragma unroll
    for (int i = 0; i < 8; ++i) acc[i] = (f32x4){0.f, 0.f, 0.f, 0.f};

#pragma unroll
    for (int kc = 0; kc < 4; ++kc){
        U128 whi[8];
#pragma unroll
        for (int nt = 0; nt < 8; ++nt)
            whi[nt].u = wf[((nt * 4 + kc) * 2 + 0) * 64 + l];
#pragma unroll
        for (int nt = 0; nt < 8; ++nt)
            acc[nt] = __builtin_amdgcn_mfma_f32_16x16x32_bf16(Ahi[kc].s, whi[nt].s, acc[nt], 0, 0, 0);
        if (MODE == 0){
#pragma unroll
            for (int nt = 0; nt < 8; ++nt)
                acc[nt] = __builtin_amdgcn_mfma_f32_16x16x32_bf16(Alo[kc].s, whi[nt].s, acc[nt], 0, 0, 0);
        }
    }

    int row0 = wtile * 16;
    if (MODE == 0){
#pragma unroll
        for (int nt = 0; nt < 8; ++nt){
            int n = nt * 16 + lanen;
            float bias = ebias[n], g = eg[n], bo = eb[n];
#pragma unroll
            for (int r = 0; r < 4; ++r){
                int grow = row0 + quad * 4 + r;
                if (grow < nrows){
                    float v = g * ((acc[nt][r] + bias) * BN_S) + bo;
                    hout[(size_t)grow * 128 + n] = fmaxf(v, 0.f);
                }
            }
        }
    } else {
#pragma unroll
        for (int nt = 0; nt < 8; ++nt){
            int n = nt * 16 + lanen;
#pragma unroll
            for (int r = 0; r < 4; ++r){
                int grow = row0 + quad * 4 + r;
                if (grow < nrows) hwout[(size_t)grow * 128 + n] = f2bs(acc[nt][r]);
            }
        }
    }
}

// ---------------- fused: gemm0 (input linear) + degree count w/ rank record ----------------
__global__ __launch_bounds__(256) void k_cg0(
    const float* __restrict__ x, const uint4* __restrict__ wf,
    const float* __restrict__ ing, const float* __restrict__ inb,
    const float* __restrict__ lb, const float* __restrict__ g0, const float* __restrict__ b0,
    float* __restrict__ hbuf, int nrows, int gb,
    const int* __restrict__ edst, int* __restrict__ cnt, int* __restrict__ rank, int E)
{
    int bid = blockIdx.x;
    if (bid < gb){
        __shared__ float sing[128], sinb[128];
        int t = threadIdx.x;
        if (t < 128){ sing[t] = ing[t] * BN_S; sinb[t] = inb[t]; }
        __syncthreads();
        int wtile = bid * 4 + (threadIdx.x >> 6);
        gemm_warp<0>(wtile, x, wf, sing, sinb, lb, g0, b0, hbuf, nullptr, nrows);
    } else {
        int base = (bid - gb) * 1024;
#pragma unroll
        for (int ii = 0; ii < 4; ++ii){
            int e = base + ii * 256 + threadIdx.x;
            if (e < E){
                int r = atomicAdd(&cnt[edst[e]], 1);
                rank[e] = r;
            }
        }
    }
}

// ---------------- fused: gemm layer-1 + CSR fill (rank-based, no atomics) ----------------
__global__ __launch_bounds__(256) void k_fg1(
    const float* __restrict__ hbuf, const uint4* __restrict__ wf,
    unsigned short* __restrict__ hwb, int nrows, int gb,
    const int* __restrict__ esrc, const int* __restrict__ edst,
    const int* __restrict__ rowptr, const int* __restrict__ rank,
    const float* __restrict__ dis, int2* __restrict__ ipk, int E)
{
    int bid = blockIdx.x;
    if (bid < gb){
        int wtile = bid * 4 + (threadIdx.x >> 6);
        gemm_warp<1>(wtile, hbuf, wf, nullptr, nullptr, nullptr, nullptr, nullptr,
                     nullptr, hwb, nrows);
    } else {
        int base = (bid - gb) * 1024;
#pragma unroll
        for (int ii = 0; ii < 4; ++ii){
            int e = base + ii * 256 + threadIdx.x;
            if (e < E){
                int s = esrc[e], d = edst[e];
                int pos = rowptr[d] + rank[e];
                ipk[pos] = make_int2(s, __float_as_int(dis[s]));
            }
        }
    }
}

// ---------------- standalone layer gemm (mode 1) ----------------
__global__ __launch_bounds__(256) void k_gemmb(
    const float* __restrict__ A, const uint4* __restrict__ wf,
    unsigned short* __restrict__ hwout, int nrows)
{
    int wtile = blockIdx.x * 4 + (threadIdx.x >> 6);
    gemm_warp<1>(wtile, A, wf, nullptr, nullptr, nullptr, nullptr, nullptr,
                 nullptr, hwout, nrows);
}

// ---------------- CSR aggregate: wave-per-row; ipk.y = dis[src], row scale applied at end ----------------
__global__ __launch_bounds__(256) void k_agg(
    const unsigned* __restrict__ hwu, float* __restrict__ h,
    const int* __restrict__ rowptr, const int2* __restrict__ ipk,
    const float* __restrict__ dis,
    const float* __restrict__ cb, const float* __restrict__ bg, const float* __restrict__ bb,
    int N)
{
    int row = blockIdx.x * 4 + (threadIdx.x >> 6);
    if (row >= N) return;
    int l = threadIdx.x & 63;
    int sub = l >> 4, cg = l & 15;
    int b = rowptr[row], e = rowptr[row + 1];
    float acc[8];
#pragma unroll
    for (int i = 0; i < 8; ++i) acc[i] = 0.f;
    for (int p = b; p < e; p += 16){
        int base = p + sub * 4;
        if (base < e){
            int2 i0 = ipk[base];
            int2 i1 = (base + 1 < e) ? ipk[base + 1] : make_int2(i0.x, 0);
            int2 i2 = (base + 2 < e) ? ipk[base + 2] : make_int2(i0.x, 0);
            int2 i3 = (base + 3 < e) ? ipk[base + 3] : make_int2(i0.x, 0);
            uint4 v0 = *(const uint4*)&hwu[(size_t)i0.x * 64 + cg * 4];
            uint4 v1 = *(const uint4*)&hwu[(size_t)i1.x * 64 + cg * 4];
            uint4 v2 = *(const uint4*)&hwu[(size_t)i2.x * 64 + cg * 4];
            uint4 v3 = *(const uint4*)&hwu[(size_t)i3.x * 64 + cg * 4];
            float c0 = __int_as_float(i0.y), c1 = __int_as_float(i1.y);
            float c2 = __int_as_float(i2.y), c3 = __int_as_float(i3.y);
            acc[0] = fmaf(ulo(v0.x), c0, acc[0]); acc[1] = fmaf(uhi(v0.x), c0, acc[1]);
            acc[2] = fmaf(ulo(v0.y), c0, acc[2]); acc[3] = fmaf(uhi(v0.y), c0, acc[3]);
            acc[4] = fmaf(ulo(v0.z), c0, acc[4]); acc[5] = fmaf(uhi(v0.z), c0, acc[5]);
            acc[6] = fmaf(ulo(v0.w), c0, acc[6]); acc[7] = fmaf(uhi(v0.w), c0, acc[7]);
            acc[0] = fmaf(ulo(v1.x), c1, acc[0]); acc[1] = fmaf(uhi(v1.x), c1, acc[1]);
            acc[2] = fmaf(ulo(v1.y), c1, acc[2]); acc[3] = fmaf(uhi(v1.y), c1, acc[3]);
            acc[4] = fmaf(ulo(v1.z), c1, acc[4]); acc[5] = fmaf(uhi(v1.z), c1, acc[5]);
            acc[6] = fmaf(ulo(v1.w), c1, acc[6]); acc[7] = fmaf(uhi(v1.w), c1, acc[7]);
            acc[0] = fmaf(ulo(v2.x), c2, acc[0]); acc[1] = fmaf(uhi(v2.x), c2, acc[1]);
            acc[2] = fmaf(ulo(v2.y), c2, acc[2]); acc[3] = fmaf(uhi(v2.y), c2, acc[3]);
            acc[4] = fmaf(ulo(v2.z), c2, acc[4]); acc[5] = fmaf(uhi(v2.z), c2, acc[5]);
            acc[6] = fmaf(ulo(v2.w), c2, acc[6]); acc[7] = fmaf(uhi(v2.w), c2, acc[7]);
            acc[0] = fmaf(ulo(v3.x), c3, acc[0]); acc[1] = fmaf(uhi(v3.x), c3, acc[1]);
            acc[2] = fmaf(ulo(v3.y), c3, acc[2]); acc[3] = fmaf(uhi(v3.y), c3, acc[3]);
            acc[4] = fmaf(ulo(v3.z), c3, acc[4]); acc[5] = fmaf(uhi(v3.z), c3, acc[5]);
            acc[6] = fmaf(ulo(v3.w), c3, acc[6]); acc[7] = fmaf(uhi(v3.w), c3, acc[7]);
        }
    }
#pragma unroll
    for (int i = 0; i < 8; ++i){
        acc[i] += __shfl_xor(acc[i], 16);
        acc[i] += __shfl_xor(acc[i], 32);
    }
    if (sub == 0){
        float d = dis[row];
        float dd = d * d;
        uint4 sv = *(const uint4*)&hwu[(size_t)row * 64 + cg * 4];
        float sf[8] = {ulo(sv.x), uhi(sv.x), ulo(sv.y), uhi(sv.y),
                       ulo(sv.z), uhi(sv.z), ulo(sv.w), uhi(sv.w)};
        float4 c0 = *(const float4*)&cb[cg * 8], c1 = *(const float4*)&cb[cg * 8 + 4];
        float4 g0 = *(const float4*)&bg[cg * 8], g1 = *(const float4*)&bg[cg * 8 + 4];
        float4 b0 = *(const float4*)&bb[cg * 8], b1 = *(const float4*)&bb[cg * 8 + 4];
        float cc[8] = {c0.x, c0.y, c0.z, c0.w, c1.x, c1.y, c1.z, c1.w};
        float gg[8] = {g0.x, g0.y, g0.z, g0.w, g1.x, g1.y, g1.z, g1.w};
        float bo[8] = {b0.x, b0.y, b0.z, b0.w, b1.x, b1.y, b1.z, b1.w};
        float4 cur0 = *(float4*)&h[(size_t)row * 128 + cg * 8];
        float4 cur1 = *(float4*)&h[(size_t)row * 128 + cg * 8 + 4];
        float o[8] = {cur0.x, cur0.y, cur0.z, cur0.w, cur1.x, cur1.y, cur1.z, cur1.w};
#pragma unroll
        for (int i = 0; i < 8; ++i){
            float v = gg[i] * ((acc[i] * d + sf[i] * dd + cc[i]) * BN_S) + bo[i];
            o[i] += fmaxf(v, 0.f);
        }
        *(float4*)&h[(size_t)row * 128 + cg * 8] = make_float4(o[0], o[1], o[2], o[3]);
        *(float4*)&h[(size_t)row * 128 + cg * 8 + 4] = make_float4(o[4], o[5], o[6], o[7]);
    }
}

// ---------------- MFMA fused heads (gather fused): 64 games/block, 4 waves x 16 games ----------------
__global__ __launch_bounds__(256) void k_headmm(
    const float* __restrict__ h, const int* __restrict__ gidx,
    const uint4* __restrict__ p1v, const uint4* __restrict__ p2v,
    const float* __restrict__ hb1, const float* __restrict__ hg1, const float* __restrict__ hbb1,
    const float* __restrict__ hb2,
    const float* __restrict__ hW3, const float* __restrict__ hb3,
    const float* __restrict__ ob1, const float* __restrict__ og1, const float* __restrict__ obb1,
    const float* __restrict__ ob2, const float* __restrict__ og2, const float* __restrict__ obb2,
    const float* __restrict__ oW3, const float* __restrict__ ob3,
    float* __restrict__ out, int G)
{
    __shared__ __align__(16) unsigned sxg[64 * 68];
    __shared__ __align__(16) unsigned sz1u[64 * 36];
    __shared__ __align__(16) unsigned sz2u[64 * 20];
    __shared__ float sb1[64], sg1[64], sbb1[64];
    __shared__ float sb2[32], sg2[32], sbb2[32];
    __shared__ float sW3[96];
    __shared__ float sb3[3];
    __shared__ int sgi[64];

    int t = threadIdx.x;
    int gblk = blockIdx.x;
    int y = blockIdx.y;
    bool bn2 = (y == 4);
    int w = t >> 6, l = t & 63;
    int lanen = l & 15, quad = l >> 4;

    const float* b1  = bn2 ? ob1  : (hb1 + y * 64);
    const float* g1  = bn2 ? og1  : (hg1 + y * 64);
    const float* bb1 = bn2 ? obb1 : (hbb1 + y * 64);
    const float* b2  = bn2 ? ob2  : (hb2 + y * 32);
    const float* W3  = bn2 ? oW3  : (hW3 + y * 32);
    const float* b3  = bn2 ? ob3  : (hb3 + y);
    int nc3 = bn2 ? 3 : 1;

    if (t < 64){
        sb1[t] = b1[t]; sg1[t] = g1[t]; sbb1[t] = bb1[t];
        if (t < 3) sb3[t] = (t < nc3) ? b3[t] : 0.f;
    } else if (t < 96){
        int p = t - 64;
        sb2[p] = b2[p];
        sg2[p] = bn2 ? og2[p] : 1.f;
        sbb2[p] = bn2 ? obb2[p] : 0.f;
    } else if (t < 192){
        int i = t - 96;
        sW3[i] = (i < 32 * nc3) ? W3[i] : 0.f;
    } else {
        int r = t - 192;
        int g = gblk * 64 + r;
        sgi[r] = (g < G) ? gidx[g] : 0;
    }
    __syncthreads();
    for (int i = t; i < 2048; i += 256){
        int r = i >> 5, c = i & 31;
        int node = sgi[r];
        float4 v = *(const float4*)&h[(size_t)node * 128 + c * 4];
        uint2 o = make_uint2((unsigned)f2bs(v.x) | ((unsigned)f2bs(v.y) << 16),
                             (unsigned)f2bs(v.z) | ((unsigned)f2bs(v.w) << 16));
        *(uint2*)&sxg[r * 68 + c * 2] = o;
    }
    __syncthreads();

    f32x4 acc1[4] = {{0.f,0.f,0.f,0.f},{0.f,0.f,0.f,0.f},{0.f,0.f,0.f,0.f},{0.f,0.f,0.f,0.f}};
#pragma unroll
    for (int kc = 0; kc < 4; ++kc){
        U128 a;
        a.u = *(const uint4*)&sxg[(w * 16 + lanen) * 68 + kc * 16 + quad * 4];
#pragma unroll
        for (int nt = 0; nt < 4; ++nt){
            U128 b;
            b.u = p1v[((y * 4 + nt) * 4 + kc) * 64 + l];
            acc1[nt] = __builtin_amdgcn_mfma_f32_16x16x32_bf16(a.s, b.s, acc1[nt], 0, 0, 0);
        }
    }
    {
        unsigned short* sz1s = (unsigned short*)sz1u;
#pragma unroll
        for (int nt = 0; nt < 4; ++nt){
            int n = nt * 16 + lanen;
            float g = sg1[n], bia = sb1[n], bt = sbb1[n];
#pragma unroll
            for (int r = 0; r < 4; ++r){
                int row = w * 16 + quad * 4 + r;
                float v = g * ((acc1[nt][r] + bia) * BN_S) + bt;
                sz1s[row * 72 + n] = f2bs(fmaxf(v, 0.f));
            }
        }
    }
    __syncthreads();

    f32x4 acc2[2] = {{0.f,0.f,0.f,0.f},{0.f,0.f,0.f,0.f}};
#pragma unroll
    for (int kc = 0; kc < 2; ++kc){
        U128 a;
        a.u = *(const uint4*)&sz1u[(w * 16 + lanen) * 36 + kc * 16 + quad * 4];
#pragma unroll
        for (int nt = 0; nt < 2; ++nt){
            U128 b;
            b.u = p2v[((y * 2 + nt) * 2 + kc) * 64 + l];
            acc2[nt] = __builtin_amdgcn_mfma_f32_16x16x32_bf16(a.s, b.s, acc2[nt], 0, 0, 0);
        }
    }
    {
        unsigned short* sz2s = (unsigned short*)sz2u;
#pragma unroll
        for (int nt = 0; nt < 2; ++nt){
            int n = nt * 16 + lanen;
            float bia = sb2[n], g = sg2[n], bt = sbb2[n];
#pragma unroll
            for (int r = 0; r < 4; ++r){
                int row = w * 16 + quad * 4 + r;
                float v = acc2[nt][r] + bia;
                if (bn2) v = g * (v * BN_S) + bt;
                sz2s[row * 40 + n] = f2bs(fmaxf(v, 0.f));
            }
        }
    }
    __syncthreads();

    const unsigned short* sz2s = (const unsigned short*)sz2u;
    if (!bn2){
        if (t < 64){
            int g = gblk * 64 + t;
            if (g < G){
                float s = sb3[0];
#pragma unroll
                for (int p = 0; p < 32; ++p) s = fmaf(bs2f(sz2s[t * 40 + p]), sW3[p], s);
                out[(size_t)g * 7 + y] = s;
            }
        }
    } else {
        if (t < 192){
            int gl = t / 3, c = t % 3;
            int g = gblk * 64 + gl;
            if (g < G){
                float s = sb3[c];
#pragma unroll
                for (int p = 0; p < 32; ++p) s = fmaf(bs2f(sz2s[gl * 40 + p]), sW3[p * 3 + c], s);
                out[(size_t)g * 7 + 4 + c] = s;
            }
        }
    }
}

extern "C" void kernel_launch(void* const* d_in, const int* in_sizes, int n_in,
                              void* d_out, int out_size, void* d_ws, size_t ws_size,
                              hipStream_t stream)
{
    const float* x    = (const float*)d_in[0];
    const int* esrc   = (const int*)d_in[1];
    const int* edst   = (const int*)d_in[2];
    const int* gidx   = (const int*)d_in[3];
    const float* in_g = (const float*)d_in[4];
    const float* in_b = (const float*)d_in[5];
    const float* lin_W = (const float*)d_in[6];
    const float* lin_b = (const float*)d_in[7];
    const float* bn0_g = (const float*)d_in[8];
    const float* bn0_b = (const float*)d_in[9];
    const float* cW[3] = {(const float*)d_in[10], (const float*)d_in[14], (const float*)d_in[18]};
    const float* cb[3] = {(const float*)d_in[11], (const float*)d_in[15], (const float*)d_in[19]};
    const float* bg[3] = {(const float*)d_in[12], (const float*)d_in[16], (const float*)d_in[20]};
    const float* bb[3] = {(const float*)d_in[13], (const float*)d_in[17], (const float*)d_in[21]};
    const float* hW1 = (const float*)d_in[22];
    const float* hb1 = (const float*)d_in[23];
    const float* hg1 = (const float*)d_in[24];
    const float* hbb1 = (const float*)d_in[25];
    const float* hW2 = (const float*)d_in[26];
    const float* hb2 = (const float*)d_in[27];
    const float* hW3 = (const float*)d_in[28];
    const float* hb3 = (const float*)d_in[29];
    const float* oW1 = (const float*)d_in[30];
    const float* ob1 = (const float*)d_in[31];
    const float* og1 = (const float*)d_in[32];
    const float* obb1 = (const float*)d_in[33];
    const float* oW2 = (const float*)d_in[34];
    const float* ob2 = (const float*)d_in[35];
    const float* og2 = (const float*)d_in[36];
    const float* obb2 = (const float*)d_in[37];
    const float* oW3 = (const float*)d_in[38];
    const float* ob3 = (const float*)d_in[39];

    const int N = in_sizes[0] / HDIM;
    const int E = in_sizes[1];
    const int G = in_sizes[3];

    char* wsp = (char*)d_ws;
    size_t off = 0;
    auto alloc = [&](size_t bytes) -> char* {
        char* p = wsp + off;
        off = (off + bytes + 255) & ~(size_t)255;
        return p;
    };
    float* dis    = (float*)alloc((size_t)N * 4);
    int* rowptr   = (int*)alloc((size_t)(N + 1) * 4);
    int* cnt      = (int*)alloc((size_t)N * 4);
    int* rank     = (int*)alloc((size_t)E * 4);
    int2* ipk     = (int2*)alloc((size_t)E * 8);
    float* hbuf   = (float*)alloc((size_t)N * HDIM * 4);
    unsigned short* hwb = (unsigned short*)alloc((size_t)N * HDIM * 2);
    unsigned short* p1 = (unsigned short*)alloc(40960 * 2);
    unsigned short* p2 = (unsigned short*)alloc(10240 * 2);
    unsigned short* wf = (unsigned short*)alloc((size_t)4 * 32768 * 2);
    int* bsum     = (int*)alloc(256 * 4);
    int* bpre     = (int*)alloc(256 * 4);

    int gb = (N + 63) / 64;         // 4 wave-tiles of 16 rows per block
    int CB = (E + 1023) / 1024;
    int B = (N + 1023) / 1024;
    int prepTot = 65536 + 51200 + N;

    // 1: zero counters + prepack all weights
    k_prepzero<<<dim3((prepTot + 255) / 256), dim3(256), 0, stream>>>(
        lin_W, cW[0], cW[1], cW[2], hW1, oW1, hW2, oW2, wf, p1, p2, cnt, N);
    // 2: gemm0 (input linear) + degree count w/ rank
    k_cg0<<<dim3(gb + CB), dim3(256), 0, stream>>>(
        x, (const uint4*)wf, in_g, in_b, lin_b, bn0_g, bn0_b, hbuf, N, gb, edst, cnt, rank, E);
    // 3-5: parallel 3-phase scan -> rowptr, dis
    k_bsum<<<dim3(B), dim3(256), 0, stream>>>(cnt, bsum, N);
    k_bscan<<<dim3(1), dim3(256), 0, stream>>>(bsum, bpre, rowptr, B, N, E);
    k_scan3<<<dim3(B), dim3(1024), 0, stream>>>(cnt, bpre, rowptr, dis, N);
    // 6: gemm layer-1 + CSR fill (no atomics)
    k_fg1<<<dim3(gb + CB), dim3(256), 0, stream>>>(
        hbuf, (const uint4*)(wf + (size_t)32768), hwb, N, gb,
        esrc, edst, rowptr, rank, dis, ipk, E);
    // 7: agg layer-1
    k_agg<<<dim3((N + 3) / 4), dim3(256), 0, stream>>>((const unsigned*)hwb, hbuf, rowptr, ipk,
                                                       dis, cb[0], bg[0], bb[0], N);
    // 8-11: layers 2,3
    for (int l = 1; l < 3; ++l){
        k_gemmb<<<dim3(gb), dim3(256), 0, stream>>>(hbuf, (const uint4*)(wf + (size_t)(1 + l) * 32768),
                                                    hwb, N);
        k_agg<<<dim3((N + 3) / 4), dim3(256), 0, stream>>>((const unsigned*)hwb, hbuf, rowptr, ipk,
                                                           dis, cb[l], bg[l], bb[l], N);
    }
    // 12: heads
    k_headmm<<<dim3((G + 63) / 64, 5), dim3(256), 0, stream>>>(
        hbuf, gidx, (const uint4*)p1, (const uint4*)p2,
        hb1, hg1, hbb1, hb2, hW3, hb3,
        ob1, og1, obb1, ob2, og2, obb2, oW3, ob3,
        (float*)d_out, G);
}

// Round 15
// 362.338 us; speedup vs baseline: 1.0507x; 1.0507x over previous
//
#include <hip/hip_runtime.h>
#include <hip/hip_bf16.h>

#define HDIM 128
static constexpr float BN_S = 0.99999500003749968751f; // 1/sqrt(1+1e-5)

typedef float f32x4 __attribute__((ext_vector_type(4)));
typedef short s16x8 __attribute__((ext_vector_type(8)));

union U128 { uint4 u; s16x8 s; };

__device__ __forceinline__ unsigned short f2bs(float f){
    union{float f; unsigned u;} c; c.f = f;
    unsigned r = c.u + 0x7fffu + ((c.u >> 16) & 1u);
    return (unsigned short)(r >> 16);
}
__device__ __forceinline__ float bs2f(unsigned short s){
    union{unsigned u; float f;} c; c.u = ((unsigned)s) << 16;
    return c.f;
}
__device__ __forceinline__ float ulo(unsigned u){ union{unsigned i; float f;} c; c.i = u << 16; return c.f; }
__device__ __forceinline__ float uhi(unsigned u){ union{unsigned i; float f;} c; c.i = u & 0xffff0000u; return c.f; }

// ---------------- zero counters + prepack all weights (one node) ----------------
__global__ __launch_bounds__(256) void k_prepzero(
    const float* __restrict__ linW, const float* __restrict__ cW1,
    const float* __restrict__ cW2, const float* __restrict__ cW3,
    const float* __restrict__ hW1, const float* __restrict__ oW1,
    const float* __restrict__ hW2, const float* __restrict__ oW2,
    unsigned short* __restrict__ wf, unsigned short* __restrict__ p1,
    unsigned short* __restrict__ p2, int* __restrict__ cnt, int N)
{
    int id = blockIdx.x * 256 + threadIdx.x;
    if (id < 65536){
        int mat = id >> 14;
        int el = id & 16383;
        int k = el >> 7, n = el & 127;
        const float* W = (mat == 0) ? linW : (mat == 1) ? cW1 : (mat == 2) ? cW2 : cW3;
        float v = W[k * 128 + n];
        unsigned short hs = f2bs(v);
        unsigned short ls = f2bs(v - bs2f(hs));
        int nt = n >> 4, lanen = n & 15, kc = k >> 5, quad = (k >> 3) & 3, j = k & 7;
        int lane = quad * 16 + lanen;
        size_t base = (size_t)mat * 32768;
        wf[base + (size_t)(((nt * 4 + kc) * 2 + 0) * 64 + lane) * 8 + j] = hs;
        wf[base + (size_t)(((nt * 4 + kc) * 2 + 1) * 64 + lane) * 8 + j] = ls;
    } else if (id < 65536 + 51200){
        int id1 = id - 65536;
        if (id1 < 40960){
            int j = id1 & 7, lane = (id1 >> 3) & 63, kc = (id1 >> 9) & 3, nt = (id1 >> 11) & 3, y = id1 >> 13;
            int k = kc * 32 + (lane >> 4) * 8 + j;
            int n = nt * 16 + (lane & 15);
            float w = (y < 4) ? hW1[(y * 128 + k) * 64 + n] : oW1[k * 64 + n];
            p1[id1] = f2bs(w);
        } else {
            int id2 = id1 - 40960;
            int j = id2 & 7, lane = (id2 >> 3) & 63, kc = (id2 >> 9) & 1, nt = (id2 >> 10) & 1, y = id2 >> 11;
            int k = kc * 32 + (lane >> 4) * 8 + j;
            int n = nt * 16 + (lane & 15);
            float w = (y < 4) ? hW2[(y * 64 + k) * 32 + n] : oW2[k * 32 + n];
            p2[id2] = f2bs(w);
        }
    } else {
        int z = id - (65536 + 51200);
        if (z < N) cnt[z] = 0;
    }
}

// ---------------- scan phase 1: per-1024-chunk sums ----------------
__global__ __launch_bounds__(256) void k_bsum(const int* __restrict__ cnt, int* __restrict__ bsum, int N){
    int b = blockIdx.x, t = threadIdx.x;
    int s = 0;
#pragma unroll
    for (int i = 0; i < 4; ++i){
        int idx = b * 1024 + i * 256 + t;
        if (idx < N) s += cnt[idx];
    }
    for (int off = 32; off; off >>= 1) s += __shfl_down(s, off);
    __shared__ int ws[4];
    if ((t & 63) == 0) ws[t >> 6] = s;
    __syncthreads();
    if (t == 0) bsum[b] = ws[0] + ws[1] + ws[2] + ws[3];
}

// ---------------- scan phase 2: single-block exclusive scan of chunk sums ----------------
__global__ __launch_bounds__(256) void k_bscan(const int* __restrict__ bsum, int* __restrict__ bpre,
                                               int* __restrict__ rowptr, int B, int N, int E){
    __shared__ int arr[256];
    int t = threadIdx.x;
    int v = (t < B) ? bsum[t] : 0;
    arr[t] = v;
    for (int off = 1; off < 256; off <<= 1){
        __syncthreads();
        int x = (t >= off) ? arr[t - off] : 0;
        __syncthreads();
        arr[t] += x;
    }
    __syncthreads();
    if (t < B) bpre[t] = arr[t] - v;
    if (t == 0) rowptr[N] = E;
}

// ---------------- scan phase 3: within-chunk scan + rowptr/dis write ----------------
__global__ __launch_bounds__(1024) void k_scan3(const int* __restrict__ cnt, const int* __restrict__ bpre,
                                                int* __restrict__ rowptr, float* __restrict__ dis, int N){
    __shared__ int arr[1024];
    int b = blockIdx.x, t = threadIdx.x;
    int idx = b * 1024 + t;
    int c = (idx < N) ? cnt[idx] : 0;
    arr[t] = c;
    for (int off = 1; off < 1024; off <<= 1){
        __syncthreads();
        int x = (t >= off) ? arr[t - off] : 0;
        __syncthreads();
        arr[t] += x;
    }
    __syncthreads();
    if (idx < N){
        rowptr[idx] = bpre[b] + arr[t] - c;
        dis[idx] = rsqrtf(1.0f + (float)c);
    }
}

// ---------------- GEMM tile device fn (LDS-staged A, coalesced LDS-transposed epilogue) ----------------
// MODE 0: A=x, input-BN fold, split-A 2-term, epilogue BN+relu -> fp32 hout (coalesced)
// MODE 1: A=h, plain bf16 single-term, epilogue raw -> bf16 hwout (coalesced)
// sbuf: MODE 0 needs 64*136 unsigned (34816 B); MODE 1 needs 64*68 unsigned (17408 B)
template<int MODE>
__device__ __forceinline__ void gemm_tile(
    int tile, const float* __restrict__ A, const uint4* __restrict__ wf,
    const float* __restrict__ ing, const float* __restrict__ inb,
    const float* __restrict__ ebias, const float* __restrict__ eg, const float* __restrict__ eb,
    float* __restrict__ hout, unsigned short* __restrict__ hwout, int nrows,
    unsigned* sbuf)
{
    unsigned* sAhi = sbuf;
    unsigned* sAlo = sbuf + 64 * 68;   // mode 0 only
    int t = threadIdx.x;
    int row0 = tile * 64;
    for (int i = t; i < 2048; i += 256){
        int r = i >> 5, q = i & 31;
        int gr = row0 + r;
        float4 v = make_float4(0.f, 0.f, 0.f, 0.f);
        if (gr < nrows) v = *(const float4*)&A[(size_t)gr * 128 + q * 4];
        if (MODE == 0){
            float4 g = *(const float4*)&ing[q * 4];
            float4 bo = *(const float4*)&inb[q * 4];
            v.x = v.x * (g.x * BN_S) + bo.x;
            v.y = v.y * (g.y * BN_S) + bo.y;
            v.z = v.z * (g.z * BN_S) + bo.z;
            v.w = v.w * (g.w * BN_S) + bo.w;
            unsigned u0 = __float_as_uint(v.x), u1 = __float_as_uint(v.y);
            unsigned u2 = __float_as_uint(v.z), u3 = __float_as_uint(v.w);
            uint2 hi = make_uint2((u0 >> 16) | (u1 & 0xffff0000u), (u2 >> 16) | (u3 & 0xffff0000u));
            unsigned short l0 = f2bs(v.x - __uint_as_float(u0 & 0xffff0000u));
            unsigned short l1 = f2bs(v.y - __uint_as_float(u1 & 0xffff0000u));
            unsigned short l2 = f2bs(v.z - __uint_as_float(u2 & 0xffff0000u));
            unsigned short l3 = f2bs(v.w - __uint_as_float(u3 & 0xffff0000u));
            uint2 lo = make_uint2((unsigned)l0 | ((unsigned)l1 << 16), (unsigned)l2 | ((unsigned)l3 << 16));
            *(uint2*)&sAhi[r * 68 + q * 2] = hi;
            *(uint2*)&sAlo[r * 68 + q * 2] = lo;
        } else {
            uint2 hi;
            hi.x = (unsigned)f2bs(v.x) | ((unsigned)f2bs(v.y) << 16);
            hi.y = (unsigned)f2bs(v.z) | ((unsigned)f2bs(v.w) << 16);
            *(uint2*)&sAhi[r * 68 + q * 2] = hi;
        }
    }
    __syncthreads();

    int w = t >> 6, l = t & 63;
    int lanen = l & 15, quad = l >> 4;
    int mrow = w * 16 + lanen;
    f32x4 acc[8];
#pragma unroll
    for (int i = 0; i < 8; ++i) acc[i] = (f32x4){0.f, 0.f, 0.f, 0.f};

    if (MODE == 0){
#pragma unroll 1
        for (int kc = 0; kc < 4; ++kc){
            U128 ahi, alo;
            ahi.u = *(const uint4*)&sAhi[mrow * 68 + kc * 16 + quad * 4];
            alo.u = *(const uint4*)&sAlo[mrow * 68 + kc * 16 + quad * 4];
            U128 whi[8];
#pragma unroll
            for (int nt = 0; nt < 8; ++nt)
                whi[nt].u = wf[((nt * 4 + kc) * 2 + 0) * 64 + l];
#pragma unroll
            for (int nt = 0; nt < 8; ++nt)
                acc[nt] = __builtin_amdgcn_mfma_f32_16x16x32_bf16(ahi.s, whi[nt].s, acc[nt], 0, 0, 0);
#pragma unroll
            for (int nt = 0; nt < 8; ++nt)
                acc[nt] = __builtin_amdgcn_mfma_f32_16x16x32_bf16(alo.s, whi[nt].s, acc[nt], 0, 0, 0);
        }
    } else {
#pragma unroll 1
        for (int kc = 0; kc < 4; ++kc){
            U128 ah;
            ah.u = *(const uint4*)&sAhi[mrow * 68 + kc * 16 + quad * 4];
            U128 wh[8];
#pragma unroll
            for (int nt = 0; nt < 8; ++nt)
                wh[nt].u = wf[((nt * 4 + kc) * 2 + 0) * 64 + l];
#pragma unroll
            for (int nt = 0; nt < 8; ++nt)
                acc[nt] = __builtin_amdgcn_mfma_f32_16x16x32_bf16(ah.s, wh[nt].s, acc[nt], 0, 0, 0);
        }
    }

    // coalesced epilogue: C tile -> LDS -> contiguous global writes
    __syncthreads();   // all waves done reading staged A
    if (MODE == 0){
        float* so = (float*)sbuf;  // 64 rows x 128 cols, stride 132 floats
#pragma unroll
        for (int nt = 0; nt < 8; ++nt){
            int n = nt * 16 + lanen;
            float bias = ebias[n], g = eg[n], bo = eb[n];
#pragma unroll
            for (int r = 0; r < 4; ++r){
                int row = w * 16 + quad * 4 + r;
                float v = g * ((acc[nt][r] + bias) * BN_S) + bo;
                so[row * 132 + n] = fmaxf(v, 0.f);
            }
        }
        __syncthreads();
        for (int i = t; i < 2048; i += 256){
            int row = i >> 5, c4 = (i & 31) * 4;
            int grow = row0 + row;
            if (grow < nrows)
                *(float4*)&hout[(size_t)grow * 128 + c4] = *(float4*)&so[row * 132 + c4];
        }
    } else {
        unsigned short* ss = (unsigned short*)sbuf;  // 64 rows x 128 shorts, stride 136
#pragma unroll
        for (int nt = 0; nt < 8; ++nt){
            int n = nt * 16 + lanen;
#pragma unroll
            for (int r = 0; r < 4; ++r){
                int row = w * 16 + quad * 4 + r;
                ss[row * 136 + n] = f2bs(acc[nt][r]);
            }
        }
        __syncthreads();
        for (int i = t; i < 1024; i += 256){
            int row = i >> 4, c = i & 15;
            int grow = row0 + row;
            if (grow < nrows)
                *(uint4*)&hwout[(size_t)grow * 128 + c * 8] = *(uint4*)&ss[row * 136 + c * 8];
        }
    }
}

// ---------------- fused: gemm0 (input linear) + degree count w/ rank record ----------------
__global__ __launch_bounds__(256) void k_cg0(
    const float* __restrict__ x, const uint4* __restrict__ wf,
    const float* __restrict__ ing, const float* __restrict__ inb,
    const float* __restrict__ lb, const float* __restrict__ g0, const float* __restrict__ b0,
    float* __restrict__ hbuf, int nrows, int gb,
    const int* __restrict__ edst, int* __restrict__ cnt, int* __restrict__ rank, int E)
{
    __shared__ __align__(16) unsigned sbuf[64 * 136];
    int bid = blockIdx.x;
    if (bid < gb){
        gemm_tile<0>(bid, x, wf, ing, inb, lb, g0, b0, hbuf, nullptr, nrows, sbuf);
    } else {
        int base = (bid - gb) * 1024;
#pragma unroll
        for (int ii = 0; ii < 4; ++ii){
            int e = base + ii * 256 + threadIdx.x;
            if (e < E){
                int r = atomicAdd(&cnt[edst[e]], 1);
                rank[e] = r;
            }
        }
    }
}

// ---------------- fused: gemm layer-1 + CSR fill (rank-based, no atomics) ----------------
__global__ __launch_bounds__(256) void k_fg1(
    const float* __restrict__ hbuf, const uint4* __restrict__ wf,
    unsigned short* __restrict__ hwb, int nrows, int gb,
    const int* __restrict__ esrc, const int* __restrict__ edst,
    const int* __restrict__ rowptr, const int* __restrict__ rank,
    const float* __restrict__ dis, int2* __restrict__ ipk, int E)
{
    __shared__ __align__(16) unsigned sbuf[64 * 68];
    int bid = blockIdx.x;
    if (bid < gb){
        gemm_tile<1>(bid, hbuf, wf, nullptr, nullptr, nullptr, nullptr, nullptr,
                     nullptr, hwb, nrows, sbuf);
    } else {
        int base = (bid - gb) * 1024;
#pragma unroll
        for (int ii = 0; ii < 4; ++ii){
            int e = base + ii * 256 + threadIdx.x;
            if (e < E){
                int s = esrc[e], d = edst[e];
                int pos = rowptr[d] + rank[e];
                ipk[pos] = make_int2(s, __float_as_int(dis[s]));
            }
        }
    }
}

// ---------------- standalone layer gemm (mode 1) ----------------
__global__ __launch_bounds__(256) void k_gemmb(
    const float* __restrict__ A, const uint4* __restrict__ wf,
    unsigned short* __restrict__ hwout, int nrows)
{
    __shared__ __align__(16) unsigned sbuf[64 * 68];
    gemm_tile<1>(blockIdx.x, A, wf, nullptr, nullptr, nullptr, nullptr, nullptr,
                 nullptr, hwout, nrows, sbuf);
}

// ---------------- CSR aggregate: wave-per-row; ipk.y = dis[src], row scale applied at end ----------------
__global__ __launch_bounds__(256) void k_agg(
    const unsigned* __restrict__ hwu, float* __restrict__ h,
    const int* __restrict__ rowptr, const int2* __restrict__ ipk,
    const float* __restrict__ dis,
    const float* __restrict__ cb, const float* __restrict__ bg, const float* __restrict__ bb,
    int N)
{
    int row = blockIdx.x * 4 + (threadIdx.x >> 6);
    if (row >= N) return;
    int l = threadIdx.x & 63;
    int sub = l >> 4, cg = l & 15;
    int b = rowptr[row], e = rowptr[row + 1];
    float acc[8];
#pragma unroll
    for (int i = 0; i < 8; ++i) acc[i] = 0.f;
    for (int p = b; p < e; p += 16){
        int base = p + sub * 4;
        if (base < e){
            int2 i0 = ipk[base];
            int2 i1 = (base + 1 < e) ? ipk[base + 1] : make_int2(i0.x, 0);
            int2 i2 = (base + 2 < e) ? ipk[base + 2] : make_int2(i0.x, 0);
            int2 i3 = (base + 3 < e) ? ipk[base + 3] : make_int2(i0.x, 0);
            uint4 v0 = *(const uint4*)&hwu[(size_t)i0.x * 64 + cg * 4];
            uint4 v1 = *(const uint4*)&hwu[(size_t)i1.x * 64 + cg * 4];
            uint4 v2 = *(const uint4*)&hwu[(size_t)i2.x * 64 + cg * 4];
            uint4 v3 = *(const uint4*)&hwu[(size_t)i3.x * 64 + cg * 4];
            float c0 = __int_as_float(i0.y), c1 = __int_as_float(i1.y);
            float c2 = __int_as_float(i2.y), c3 = __int_as_float(i3.y);
            acc[0] = fmaf(ulo(v0.x), c0, acc[0]); acc[1] = fmaf(uhi(v0.x), c0, acc[1]);
            acc[2] = fmaf(ulo(v0.y), c0, acc[2]); acc[3] = fmaf(uhi(v0.y), c0, acc[3]);
            acc[4] = fmaf(ulo(v0.z), c0, acc[4]); acc[5] = fmaf(uhi(v0.z), c0, acc[5]);
            acc[6] = fmaf(ulo(v0.w), c0, acc[6]); acc[7] = fmaf(uhi(v0.w), c0, acc[7]);
            acc[0] = fmaf(ulo(v1.x), c1, acc[0]); acc[1] = fmaf(uhi(v1.x), c1, acc[1]);
            acc[2] = fmaf(ulo(v1.y), c1, acc[2]); acc[3] = fmaf(uhi(v1.y), c1, acc[3]);
            acc[4] = fmaf(ulo(v1.z), c1, acc[4]); acc[5] = fmaf(uhi(v1.z), c1, acc[5]);
            acc[6] = fmaf(ulo(v1.w), c1, acc[6]); acc[7] = fmaf(uhi(v1.w), c1, acc[7]);
            acc[0] = fmaf(ulo(v2.x), c2, acc[0]); acc[1] = fmaf(uhi(v2.x), c2, acc[1]);
            acc[2] = fmaf(ulo(v2.y), c2, acc[2]); acc[3] = fmaf(uhi(v2.y), c2, acc[3]);
            acc[4] = fmaf(ulo(v2.z), c2, acc[4]); acc[5] = fmaf(uhi(v2.z), c2, acc[5]);
            acc[6] = fmaf(ulo(v2.w), c2, acc[6]); acc[7] = fmaf(uhi(v2.w), c2, acc[7]);
            acc[0] = fmaf(ulo(v3.x), c3, acc[0]); acc[1] = fmaf(uhi(v3.x), c3, acc[1]);
            acc[2] = fmaf(ulo(v3.y), c3, acc[2]); acc[3] = fmaf(uhi(v3.y), c3, acc[3]);
            acc[4] = fmaf(ulo(v3.z), c3, acc[4]); acc[5] = fmaf(uhi(v3.z), c3, acc[5]);
            acc[6] = fmaf(ulo(v3.w), c3, acc[6]); acc[7] = fmaf(uhi(v3.w), c3, acc[7]);
        }
    }
#pragma unroll
    for (int i = 0; i < 8; ++i){
        acc[i] += __shfl_xor(acc[i], 16);
        acc[i] += __shfl_xor(acc[i], 32);
    }
    if (sub == 0){
        float d = dis[row];
        float dd = d * d;
        uint4 sv = *(const uint4*)&hwu[(size_t)row * 64 + cg * 4];
        float sf[8] = {ulo(sv.x), uhi(sv.x), ulo(sv.y), uhi(sv.y),
                       ulo(sv.z), uhi(sv.z), ulo(sv.w), uhi(sv.w)};
        float4 c0 = *(const float4*)&cb[cg * 8], c1 = *(const float4*)&cb[cg * 8 + 4];
        float4 g0 = *(const float4*)&bg[cg * 8], g1 = *(const float4*)&bg[cg * 8 + 4];
        float4 b0 = *(const float4*)&bb[cg * 8], b1 = *(const float4*)&bb[cg * 8 + 4];
        float cc[8] = {c0.x, c0.y, c0.z, c0.w, c1.x, c1.y, c1.z, c1.w};
        float gg[8] = {g0.x, g0.y, g0.z, g0.w, g1.x, g1.y, g1.z, g1.w};
        float bo[8] = {b0.x, b0.y, b0.z, b0.w, b1.x, b1.y, b1.z, b1.w};
        float4 cur0 = *(float4*)&h[(size_t)row * 128 + cg * 8];
        float4 cur1 = *(float4*)&h[(size_t)row * 128 + cg * 8 + 4];
        float o[8] = {cur0.x, cur0.y, cur0.z, cur0.w, cur1.x, cur1.y, cur1.z, cur1.w};
#pragma unroll
        for (int i = 0; i < 8; ++i){
            float v = gg[i] * ((acc[i] * d + sf[i] * dd + cc[i]) * BN_S) + bo[i];
            o[i] += fmaxf(v, 0.f);
        }
        *(float4*)&h[(size_t)row * 128 + cg * 8] = make_float4(o[0], o[1], o[2], o[3]);
        *(float4*)&h[(size_t)row * 128 + cg * 8 + 4] = make_float4(o[4], o[5], o[6], o[7]);
    }
}

// ---------------- MFMA fused heads (gather fused): 64 games/block, 4 waves x 16 games ----------------
__global__ __launch_bounds__(256) void k_headmm(
    const float* __restrict__ h, const int* __restrict__ gidx,
    const uint4* __restrict__ p1v, const uint4* __restrict__ p2v,
    const float* __restrict__ hb1, const float* __restrict__ hg1, const float* __restrict__ hbb1,
    const float* __restrict__ hb2,
    const float* __restrict__ hW3, const float* __restrict__ hb3,
    const float* __restrict__ ob1, const float* __restrict__ og1, const float* __restrict__ obb1,
    const float* __restrict__ ob2, const float* __restrict__ og2, const float* __restrict__ obb2,
    const float* __restrict__ oW3, const float* __restrict__ ob3,
    float* __restrict__ out, int G)
{
    __shared__ __align__(16) unsigned sxg[64 * 68];
    __shared__ __align__(16) unsigned sz1u[64 * 36];
    __shared__ __align__(16) unsigned sz2u[64 * 20];
    __shared__ float sb1[64], sg1[64], sbb1[64];
    __shared__ float sb2[32], sg2[32], sbb2[32];
    __shared__ float sW3[96];
    __shared__ float sb3[3];
    __shared__ int sgi[64];

    int t = threadIdx.x;
    int gblk = blockIdx.x;
    int y = blockIdx.y;
    bool bn2 = (y == 4);
    int w = t >> 6, l = t & 63;
    int lanen = l & 15, quad = l >> 4;

    const float* b1  = bn2 ? ob1  : (hb1 + y * 64);
    const float* g1  = bn2 ? og1  : (hg1 + y * 64);
    const float* bb1 = bn2 ? obb1 : (hbb1 + y * 64);
    const float* b2  = bn2 ? ob2  : (hb2 + y * 32);
    const float* W3  = bn2 ? oW3  : (hW3 + y * 32);
    const float* b3  = bn2 ? ob3  : (hb3 + y);
    int nc3 = bn2 ? 3 : 1;

    if (t < 64){
        sb1[t] = b1[t]; sg1[t] = g1[t]; sbb1[t] = bb1[t];
        if (t < 3) sb3[t] = (t < nc3) ? b3[t] : 0.f;
    } else if (t < 96){
        int p = t - 64;
        sb2[p] = b2[p];
        sg2[p] = bn2 ? og2[p] : 1.f;
        sbb2[p] = bn2 ? obb2[p] : 0.f;
    } else if (t < 192){
        int i = t - 96;
        sW3[i] = (i < 32 * nc3) ? W3[i] : 0.f;
    } else {
        int r = t - 192;
        int g = gblk * 64 + r;
        sgi[r] = (g < G) ? gidx[g] : 0;
    }
    __syncthreads();
    for (int i = t; i < 2048; i += 256){
        int r = i >> 5, c = i & 31;
        int node = sgi[r];
        float4 v = *(const float4*)&h[(size_t)node * 128 + c * 4];
        uint2 o = make_uint2((unsigned)f2bs(v.x) | ((unsigned)f2bs(v.y) << 16),
                             (unsigned)f2bs(v.z) | ((unsigned)f2bs(v.w) << 16));
        *(uint2*)&sxg[r * 68 + c * 2] = o;
    }
    __syncthreads();

    f32x4 acc1[4] = {{0.f,0.f,0.f,0.f},{0.f,0.f,0.f,0.f},{0.f,0.f,0.f,0.f},{0.f,0.f,0.f,0.f}};
#pragma unroll
    for (int kc = 0; kc < 4; ++kc){
        U128 a;
        a.u = *(const uint4*)&sxg[(w * 16 + lanen) * 68 + kc * 16 + quad * 4];
#pragma unroll
        for (int nt = 0; nt < 4; ++nt){
            U128 b;
            b.u = p1v[((y * 4 + nt) * 4 + kc) * 64 + l];
            acc1[nt] = __builtin_amdgcn_mfma_f32_16x16x32_bf16(a.s, b.s, acc1[nt], 0, 0, 0);
        }
    }
    {
        unsigned short* sz1s = (unsigned short*)sz1u;
#pragma unroll
        for (int nt = 0; nt < 4; ++nt){
            int n = nt * 16 + lanen;
            float g = sg1[n], bia = sb1[n], bt = sbb1[n];
#pragma unroll
            for (int r = 0; r < 4; ++r){
                int row = w * 16 + quad * 4 + r;
                float v = g * ((acc1[nt][r] + bia) * BN_S) + bt;
                sz1s[row * 72 + n] = f2bs(fmaxf(v, 0.f));
            }
        }
    }
    __syncthreads();

    f32x4 acc2[2] = {{0.f,0.f,0.f,0.f},{0.f,0.f,0.f,0.f}};
#pragma unroll
    for (int kc = 0; kc < 2; ++kc){
        U128 a;
        a.u = *(const uint4*)&sz1u[(w * 16 + lanen) * 36 + kc * 16 + quad * 4];
#pragma unroll
        for (int nt = 0; nt < 2; ++nt){
            U128 b;
            b.u = p2v[((y * 2 + nt) * 2 + kc) * 64 + l];
            acc2[nt] = __builtin_amdgcn_mfma_f32_16x16x32_bf16(a.s, b.s, acc2[nt], 0, 0, 0);
        }
    }
    {
        unsigned short* sz2s = (unsigned short*)sz2u;
#pragma unroll
        for (int nt = 0; nt < 2; ++nt){
            int n = nt * 16 + lanen;
            float bia = sb2[n], g = sg2[n], bt = sbb2[n];
#pragma unroll
            for (int r = 0; r < 4; ++r){
                int row = w * 16 + quad * 4 + r;
                float v = acc2[nt][r] + bia;
                if (bn2) v = g * (v * BN_S) + bt;
                sz2s[row * 40 + n] = f2bs(fmaxf(v, 0.f));
            }
        }
    }
    __syncthreads();

    const unsigned short* sz2s = (const unsigned short*)sz2u;
    if (!bn2){
        if (t < 64){
            int g = gblk * 64 + t;
            if (g < G){
                float s = sb3[0];
#pragma unroll
                for (int p = 0; p < 32; ++p) s = fmaf(bs2f(sz2s[t * 40 + p]), sW3[p], s);
                out[(size_t)g * 7 + y] = s;
            }
        }
    } else {
        if (t < 192){
            int gl = t / 3, c = t % 3;
            int g = gblk * 64 + gl;
            if (g < G){
                float s = sb3[c];
#pragma unroll
                for (int p = 0; p < 32; ++p) s = fmaf(bs2f(sz2s[gl * 40 + p]), sW3[p * 3 + c], s);
                out[(size_t)g * 7 + 4 + c] = s;
            }
        }
    }
}

extern "C" void kernel_launch(void* const* d_in, const int* in_sizes, int n_in,
                              void* d_out, int out_size, void* d_ws, size_t ws_size,
                              hipStream_t stream)
{
    const float* x    = (const float*)d_in[0];
    const int* esrc   = (const int*)d_in[1];
    const int* edst   = (const int*)d_in[2];
    const int* gidx   = (const int*)d_in[3];
    const float* in_g = (const float*)d_in[4];
    const float* in_b = (const float*)d_in[5];
    const float* lin_W = (const float*)d_in[6];
    const float* lin_b = (const float*)d_in[7];
    const float* bn0_g = (const float*)d_in[8];
    const float* bn0_b = (const float*)d_in[9];
    const float* cW[3] = {(const float*)d_in[10], (const float*)d_in[14], (const float*)d_in[18]};
    const float* cb[3] = {(const float*)d_in[11], (const float*)d_in[15], (const float*)d_in[19]};
    const float* bg[3] = {(const float*)d_in[12], (const float*)d_in[16], (const float*)d_in[20]};
    const float* bb[3] = {(const float*)d_in[13], (const float*)d_in[17], (const float*)d_in[21]};
    const float* hW1 = (const float*)d_in[22];
    const float* hb1 = (const float*)d_in[23];
    const float* hg1 = (const float*)d_in[24];
    const float* hbb1 = (const float*)d_in[25];
    const float* hW2 = (const float*)d_in[26];
    const float* hb2 = (const float*)d_in[27];
    const float* hW3 = (const float*)d_in[28];
    const float* hb3 = (const float*)d_in[29];
    const float* oW1 = (const float*)d_in[30];
    const float* ob1 = (const float*)d_in[31];
    const float* og1 = (const float*)d_in[32];
    const float* obb1 = (const float*)d_in[33];
    const float* oW2 = (const float*)d_in[34];
    const float* ob2 = (const float*)d_in[35];
    const float* og2 = (const float*)d_in[36];
    const float* obb2 = (const float*)d_in[37];
    const float* oW3 = (const float*)d_in[38];
    const float* ob3 = (const float*)d_in[39];

    const int N = in_sizes[0] / HDIM;
    const int E = in_sizes[1];
    const int G = in_sizes[3];

    char* wsp = (char*)d_ws;
    size_t off = 0;
    auto alloc = [&](size_t bytes) -> char* {
        char* p = wsp + off;
        off = (off + bytes + 255) & ~(size_t)255;
        return p;
    };
    float* dis    = (float*)alloc((size_t)N * 4);
    int* rowptr   = (int*)alloc((size_t)(N + 1) * 4);
    int* cnt      = (int*)alloc((size_t)N * 4);
    int* rank     = (int*)alloc((size_t)E * 4);
    int2* ipk     = (int2*)alloc((size_t)E * 8);
    float* hbuf   = (float*)alloc((size_t)N * HDIM * 4);
    unsigned short* hwb = (unsigned short*)alloc((size_t)N * HDIM * 2);
    unsigned short* p1 = (unsigned short*)alloc(40960 * 2);
    unsigned short* p2 = (unsigned short*)alloc(10240 * 2);
    unsigned short* wf = (unsigned short*)alloc((size_t)4 * 32768 * 2);
    int* bsum     = (int*)alloc(256 * 4);
    int* bpre     = (int*)alloc(256 * 4);

    int gb = (N + 63) / 64;
    int CB = (E + 1023) / 1024;
    int B = (N + 1023) / 1024;
    int prepTot = 65536 + 51200 + N;

    // 1: zero counters + prepack all weights
    k_prepzero<<<dim3((prepTot + 255) / 256), dim3(256), 0, stream>>>(
        lin_W, cW[0], cW[1], cW[2], hW1, oW1, hW2, oW2, wf, p1, p2, cnt, N);
    // 2: gemm0 (input linear, split-A x bf16-W) + degree count w/ rank
    k_cg0<<<dim3(gb + CB), dim3(256), 0, stream>>>(
        x, (const uint4*)wf, in_g, in_b, lin_b, bn0_g, bn0_b, hbuf, N, gb, edst, cnt, rank, E);
    // 3-5: parallel 3-phase scan -> rowptr, dis
    k_bsum<<<dim3(B), dim3(256), 0, stream>>>(cnt, bsum, N);
    k_bscan<<<dim3(1), dim3(256), 0, stream>>>(bsum, bpre, rowptr, B, N, E);
    k_scan3<<<dim3(B), dim3(1024), 0, stream>>>(cnt, bpre, rowptr, dis, N);
    // 6: gemm layer-1 + CSR fill (no atomics)
    k_fg1<<<dim3(gb + CB), dim3(256), 0, stream>>>(
        hbuf, (const uint4*)(wf + (size_t)32768), hwb, N, gb,
        esrc, edst, rowptr, rank, dis, ipk, E);
    // 7: agg layer-1
    k_agg<<<dim3((N + 3) / 4), dim3(256), 0, stream>>>((const unsigned*)hwb, hbuf, rowptr, ipk,
                                                       dis, cb[0], bg[0], bb[0], N);
    // 8-11: layers 2,3
    for (int l = 1; l < 3; ++l){
        k_gemmb<<<dim3(gb), dim3(256), 0, stream>>>(hbuf, (const uint4*)(wf + (size_t)(1 + l) * 32768),
                                                    hwb, N);
        k_agg<<<dim3((N + 3) / 4), dim3(256), 0, stream>>>((const unsigned*)hwb, hbuf, rowptr, ipk,
                                                           dis, cb[l], bg[l], bb[l], N);
    }
    // 12: heads
    k_headmm<<<dim3((G + 63) / 64, 5), dim3(256), 0, stream>>>(
        hbuf, gidx, (const uint4*)p1, (const uint4*)p2,
        hb1, hg1, hbb1, hb2, hW3, hb3,
        ob1, og1, obb1, ob2, og2, obb2, oW3, ob3,
        (float*)d_out, G);
}